// Round 2
// baseline (1924.195 us; speedup 1.0000x reference)
//
#include <hip/hip_runtime.h>

// SubsetGFlowNetTB: 17-step GFlowNet trajectory-balance forward.
// State (sel_mask, k, step) depends only on `actions`, so layer-1 is an
// incremental running sum of W1 rows; layers 2/3 are bf16 MFMA GEMMs.
// R1: single shared h buffer (LDS 85.5->52KB => 2 blocks/CU), one-pass
// per-wave online softmax, conflict-free stop-logit dot.

#define NEG_INF (-1000000000.0f)

typedef short bf16x8 __attribute__((ext_vector_type(8)));
typedef float f32x16 __attribute__((ext_vector_type(16)));

__device__ __forceinline__ unsigned short f2bf(float x){
  unsigned int u = __float_as_uint(x);
  u = (u + 0x7FFFu + ((u >> 16) & 1u)) >> 16;   // round-to-nearest-even
  return (unsigned short)u;
}
__device__ __forceinline__ float bf2f(unsigned short h){
  return __uint_as_float(((unsigned int)h) << 16);
}

// ---------------------------------------------------------------------------
// Prep: W2 (256x256 f32), Wh (256x513 f32) -> bf16 MFMA B-fragments for
// v_mfma_f32_32x32x16_bf16. Lane l of tile (kt,ntg) holds
// B[kt*16 + (l>>5)*8 + i][ntg*32 + (l&31)], i=0..7.
// ---------------------------------------------------------------------------
__global__ void prep_kernel(const float* __restrict__ W2, const float* __restrict__ Wh,
                            unsigned short* __restrict__ w2f, unsigned short* __restrict__ whf,
                            float* __restrict__ whstop){
  int id = blockIdx.x * 256 + threadIdx.x;
  if (id < 8192){                       // W2 fragments
    int lane = id & 63; int tile = id >> 6;   // tile = kt*8 + ntg
    int ntg = tile & 7, kt = tile >> 3;
    int col = ntg * 32 + (lane & 31);
    int k0  = kt * 16 + (lane >> 5) * 8;
    unsigned int u[4];
#pragma unroll
    for (int p = 0; p < 4; ++p){
      unsigned short lo = f2bf(W2[(k0 + 2*p    ) * 256 + col]);
      unsigned short hi = f2bf(W2[(k0 + 2*p + 1) * 256 + col]);
      u[p] = (unsigned int)lo | ((unsigned int)hi << 16);
    }
    *(uint4*)(w2f + (size_t)id * 8) = make_uint4(u[0], u[1], u[2], u[3]);
  } else if (id < 24576){               // Wh fragments (asset cols 0..511)
    int id2 = id - 8192;
    int lane = id2 & 63; int tile = id2 >> 6; // tile = kt*16 + ntg
    int ntg = tile & 15, kt = tile >> 4;
    int col = ntg * 32 + (lane & 31);
    int k0  = kt * 16 + (lane >> 5) * 8;
    unsigned int u[4];
#pragma unroll
    for (int p = 0; p < 4; ++p){
      unsigned short lo = f2bf(Wh[(k0 + 2*p    ) * 513 + col]);
      unsigned short hi = f2bf(Wh[(k0 + 2*p + 1) * 513 + col]);
      u[p] = (unsigned int)lo | ((unsigned int)hi << 16);
    }
    *(uint4*)(whf + (size_t)id2 * 8) = make_uint4(u[0], u[1], u[2], u[3]);
  } else if (id < 24832){               // stop column, f32
    int k = id - 24576;
    whstop[k] = Wh[k * 513 + 512];
  }
}

// ---------------------------------------------------------------------------
// Fused kernel: 512 threads (8 waves) own 64 samples, loop 17 steps.
// Single LDS h tile [64][256] bf16, byte-XOR swizzle ((row&7)<<4).
// ---------------------------------------------------------------------------
__launch_bounds__(512, 4)
__global__ void gfn_kernel(const int* __restrict__ actions, const float* __restrict__ rp,
                           const float* __restrict__ W1, const float* __restrict__ b1,
                           const float* __restrict__ b2, const float* __restrict__ bh,
                           const unsigned short* __restrict__ w2f,
                           const unsigned short* __restrict__ whf,
                           const float* __restrict__ whstop,
                           float* __restrict__ out)
{
  __shared__ alignas(16) unsigned short h[64 * 256];    // 32 KB (h1 then h2)
  __shared__ float c_lds[1024];          // rows W1[512..514] + b1
  __shared__ float b2_s[256];
  __shared__ float bh_s[513];
  __shared__ unsigned long long selw[64][8];
  __shared__ float pred_m[64][8];
  __shared__ float pred_s[64][8];
  __shared__ float stopl[64];
  __shared__ float chosen[64];
  __shared__ float logpf_s[64];
  __shared__ float rp_s[64];
  __shared__ int   kcnt[64];
  __shared__ int   isnew_s[64];
  __shared__ int   act_s[64 * 17];

  const int tid  = threadIdx.x;
  const int wave = tid >> 6;
  const int lane = tid & 63;
  const int ln5  = lane & 31;
  const int lg2  = lane >> 5;
  const int base = blockIdx.x * 64;

  // ---- init ----
  for (int i = tid; i < 1024; i += 512){
    int rrow = i >> 8, f = i & 255;
    c_lds[i] = (rrow < 3) ? W1[(512 + rrow) * 256 + f] : b1[f];
  }
  if (tid < 256) b2_s[tid] = b2[tid];
  for (int i = tid; i < 513; i += 512) bh_s[i] = bh[i];
  selw[tid >> 3][tid & 7] = 0ULL;
  if (tid < 64){
    kcnt[tid] = 0; logpf_s[tid] = 0.f; rp_s[tid] = rp[base + tid];
  }
  for (int i = tid; i < 64 * 17; i += 512) act_s[i] = actions[base * 17 + i];
  float S[32];
#pragma unroll
  for (int j = 0; j < 32; ++j) S[j] = 0.f;
  __syncthreads();

  char* hb = (char*)h;

  for (int t = 0; t < 17; ++t){
    // ---- Phase A: h1 = relu(x@W1 + b1); thread = (sample=lane, feats wave*32..)
    {
      float kf = (float)kcnt[lane];
      float rv = rp_s[lane];
      float tf = (float)t;
      unsigned int packed[16];
#pragma unroll
      for (int j = 0; j < 16; ++j){
        int f = wave * 32 + 2 * j;
        float v0 = S[2*j]   + kf * c_lds[f]   + tf * c_lds[256 + f]   + rv * c_lds[512 + f]   + c_lds[768 + f];
        float v1 = S[2*j+1] + kf * c_lds[f+1] + tf * c_lds[256 + f+1] + rv * c_lds[512 + f+1] + c_lds[768 + f+1];
        v0 = fmaxf(v0, 0.f); v1 = fmaxf(v1, 0.f);
        packed[j] = (unsigned int)f2bf(v0) | ((unsigned int)f2bf(v1) << 16);
      }
#pragma unroll
      for (int c = 0; c < 4; ++c){
        int byte = (lane * 512 + wave * 64 + c * 16) ^ ((lane & 7) << 4);
        *(uint4*)(hb + byte) = make_uint4(packed[4*c], packed[4*c+1], packed[4*c+2], packed[4*c+3]);
      }
    }
    __syncthreads();

    // ---- Phase B: h2 = relu(h1 @ W2 + b2); wave owns cols [wave*32, +32)
    {
      f32x16 acc0, acc1;
#pragma unroll
      for (int i = 0; i < 16; ++i){ acc0[i] = 0.f; acc1[i] = 0.f; }
#pragma unroll 4
      for (int kt = 0; kt < 16; ++kt){
        int kb = kt * 32 + lg2 * 16;
        int row0 = ln5, row1 = 32 + ln5;
        bf16x8 a0 = *(const bf16x8*)(hb + ((row0 * 512 + kb) ^ ((row0 & 7) << 4)));
        bf16x8 a1 = *(const bf16x8*)(hb + ((row1 * 512 + kb) ^ ((row1 & 7) << 4)));
        bf16x8 b  = *(const bf16x8*)(w2f + ((size_t)((kt * 8 + wave) * 64 + lane)) * 8);
        acc0 = __builtin_amdgcn_mfma_f32_32x32x16_bf16(a0, b, acc0, 0, 0, 0);
        acc1 = __builtin_amdgcn_mfma_f32_32x32x16_bf16(a1, b, acc1, 0, 0, 0);
      }
      __syncthreads();   // all h1 reads done before overwriting with h2
      int col = wave * 32 + ln5;
      float bias = b2_s[col];
#pragma unroll
      for (int r = 0; r < 16; ++r){
        int row = (r & 3) + ((r >> 2) << 3) + (lg2 << 2);  // D: row=(reg&3)+8*(reg>>2)+4*(lane>>5)
        float v0 = fmaxf(acc0[r] + bias, 0.f);
        *(unsigned short*)(hb + ((row * 512 + col * 2) ^ ((row & 7) << 4))) = f2bf(v0);
        int row1 = row + 32;
        float v1 = fmaxf(acc1[r] + bias, 0.f);
        *(unsigned short*)(hb + ((row1 * 512 + col * 2) ^ ((row1 & 7) << 4))) = f2bf(v1);
      }
    }
    __syncthreads();

    // ---- Phase C: logits = h2 @ Wh + bh, mask, online softmax, gather ----
    // stop logit (col 512): 8 threads/sample, contiguous 16B slots (bank-clean)
    {
      int s = tid >> 3, f8 = tid & 7;
      float sp = 0.f;
#pragma unroll
      for (int c = 0; c < 4; ++c){
        int byte = (s * 512 + c * 128 + f8 * 16) ^ ((s & 7) << 4);
        uint4 q = *(const uint4*)(hb + byte);
        unsigned int qq[4] = {q.x, q.y, q.z, q.w};
#pragma unroll
        for (int p = 0; p < 4; ++p){
          int f = c * 64 + f8 * 8 + 2 * p;
          sp += bf2f((unsigned short)(qq[p] & 0xFFFFu)) * whstop[f]
              + bf2f((unsigned short)(qq[p] >> 16))     * whstop[f + 1];
        }
      }
      sp += __shfl_xor(sp, 1);
      sp += __shfl_xor(sp, 2);
      sp += __shfl_xor(sp, 4);
      if (f8 == 0){
        float v = sp + bh_s[512];
        if (kcnt[s] == 0) v = NEG_INF;   // mask_stop: k>0 required
        stopl[s] = v;
      }
    }

    // asset logits: wave owns cols [wave*64, +64): 2 row-tiles x 2 col-tiles
    f32x16 accC[2][2];
#pragma unroll
    for (int i = 0; i < 16; ++i){
      accC[0][0][i] = 0.f; accC[0][1][i] = 0.f; accC[1][0][i] = 0.f; accC[1][1][i] = 0.f;
    }
#pragma unroll 4
    for (int kt = 0; kt < 16; ++kt){
      int kb = kt * 32 + lg2 * 16;
      int row0 = ln5, row1 = 32 + ln5;
      bf16x8 a0 = *(const bf16x8*)(hb + ((row0 * 512 + kb) ^ ((row0 & 7) << 4)));
      bf16x8 a1 = *(const bf16x8*)(hb + ((row1 * 512 + kb) ^ ((row1 & 7) << 4)));
      bf16x8 b0 = *(const bf16x8*)(whf + ((size_t)((kt * 16 + wave * 2 + 0) * 64 + lane)) * 8);
      bf16x8 b1 = *(const bf16x8*)(whf + ((size_t)((kt * 16 + wave * 2 + 1) * 64 + lane)) * 8);
      accC[0][0] = __builtin_amdgcn_mfma_f32_32x32x16_bf16(a0, b0, accC[0][0], 0, 0, 0);
      accC[1][0] = __builtin_amdgcn_mfma_f32_32x32x16_bf16(a1, b0, accC[1][0], 0, 0, 0);
      accC[0][1] = __builtin_amdgcn_mfma_f32_32x32x16_bf16(a0, b1, accC[0][1], 0, 0, 0);
      accC[1][1] = __builtin_amdgcn_mfma_f32_32x32x16_bf16(a1, b1, accC[1][1], 0, 0, 0);
    }

    // single fused pass: bias + mask + chosen-gather + per-wave online (m, sumexp)
#pragma unroll
    for (int mt = 0; mt < 2; ++mt){
#pragma unroll
      for (int r = 0; r < 16; ++r){
        int row = mt * 32 + (r & 3) + ((r >> 2) << 3) + (lg2 << 2);
        unsigned long long sw = selw[row][wave];   // this wave's 64-col word
        bool full = (kcnt[row] >= 16);
        int arow = act_s[row * 17 + t];
        int col0 = wave * 64 + ln5;
        int col1 = col0 + 32;
        float v0 = accC[mt][0][r] + bh_s[col0];
        float v1 = accC[mt][1][r] + bh_s[col1];
        bool m0 = full || ((sw >> ln5) & 1ULL);
        bool m1 = full || ((sw >> (32 + ln5)) & 1ULL);
        v0 = m0 ? NEG_INF : v0;
        v1 = m1 ? NEG_INF : v1;
        if (col0 == arow) chosen[row] = v0;
        if (col1 == arow) chosen[row] = v1;
        float vm = fmaxf(v0, v1);
        vm = fmaxf(vm, __shfl_xor(vm, 1));
        vm = fmaxf(vm, __shfl_xor(vm, 2));
        vm = fmaxf(vm, __shfl_xor(vm, 4));
        vm = fmaxf(vm, __shfl_xor(vm, 8));
        vm = fmaxf(vm, __shfl_xor(vm, 16));
        float ps = __expf(v0 - vm) + __expf(v1 - vm);
        ps += __shfl_xor(ps, 1);
        ps += __shfl_xor(ps, 2);
        ps += __shfl_xor(ps, 4);
        ps += __shfl_xor(ps, 8);
        ps += __shfl_xor(ps, 16);
        if (ln5 == 0){ pred_m[row][wave] = vm; pred_s[row][wave] = ps; }
      }
    }
    __syncthreads();

    // finalize row: merge 8 wave-partials + stop, lse, logpf, state update
    if (tid < 64){
      int row = tid;
      float m = stopl[row];
#pragma unroll
      for (int w = 0; w < 8; ++w) m = fmaxf(m, pred_m[row][w]);
      float tot = __expf(stopl[row] - m);
#pragma unroll
      for (int w = 0; w < 8; ++w) tot += pred_s[row][w] * __expf(pred_m[row][w] - m);
      float lse = m + __logf(tot);
      int a = act_s[row * 17 + t];
      if (a >= 0){
        float cv = (a >= 512) ? stopl[row] : chosen[row];
        logpf_s[row] += cv - lse;
      }
      int isn = 0;
      if (a >= 0 && a < 512){
        unsigned long long old = selw[row][a >> 6];
        if (!((old >> (a & 63)) & 1ULL)){
          isn = 1;
          selw[row][a >> 6] = old | (1ULL << (a & 63));
          kcnt[row] = kcnt[row] + 1;
        }
      }
      isnew_s[row] = isn;
    }
    __syncthreads();

    // layer-1 running-sum update: S += W1[a,:] if newly selected
    if (isnew_s[lane]){
      int a = act_s[lane * 17 + t];
      const float* wr = W1 + (size_t)a * 256 + wave * 32;
#pragma unroll
      for (int c = 0; c < 8; ++c){
        float4 v = *(const float4*)(wr + c * 4);
        S[c*4+0] += v.x; S[c*4+1] += v.y; S[c*4+2] += v.z; S[c*4+3] += v.w;
      }
    }
  } // step loop

  if (tid < 64) out[base + tid] = logpf_s[tid];
}

extern "C" void kernel_launch(void* const* d_in, const int* in_sizes, int n_in,
                              void* d_out, int out_size, void* d_ws, size_t ws_size,
                              hipStream_t stream)
{
  const int*   actions = (const int*)d_in[0];
  const float* rp  = (const float*)d_in[1];
  const float* W1  = (const float*)d_in[2];
  const float* b1  = (const float*)d_in[3];
  const float* W2  = (const float*)d_in[4];
  const float* b2  = (const float*)d_in[5];
  const float* Wh  = (const float*)d_in[6];
  const float* bh  = (const float*)d_in[7];
  float* out = (float*)d_out;

  unsigned short* w2f = (unsigned short*)d_ws;          // 65536  bf16 (128 KB)
  unsigned short* whf = w2f + 65536;                    // 131072 bf16 (256 KB)
  float* whstop = (float*)(whf + 131072);               // 256 f32

  prep_kernel<<<97, 256, 0, stream>>>(W2, Wh, w2f, whf, whstop);
  gfn_kernel<<<1024, 512, 0, stream>>>(actions, rp, W1, b1, b2, bh, w2f, whf, whstop, out);
}

// Round 3
// 1078.962 us; speedup vs baseline: 1.7834x; 1.7834x over previous
//
#include <hip/hip_runtime.h>

// SubsetGFlowNetTB: 17-step GFlowNet trajectory-balance forward.
// State (sel_mask, k, step) depends only on `actions`, so layer-1 is an
// incremental running sum of W1 rows; layers 2/3 are bf16 MFMA GEMMs.
// R3: launch_bounds(512,2) [R2's (512,4) forced VGPR=64 -> 3.2GB spill],
// no-max softmax (logits O(1), masked exp underflows to 0), phase C re-tiled
// 1 row-tile x 4 col-tiles (5 shuffles/r instead of 10, 16 r instead of 32),
// phase A feat-per-lane (c-coefs via 4x ds_read_b128), meta/selw packed reads.

#define NEG_INF (-1000000000.0f)

typedef short bf16x8 __attribute__((ext_vector_type(8)));
typedef float f32x16 __attribute__((ext_vector_type(16)));

__device__ __forceinline__ unsigned short f2bf(float x){
  unsigned int u = __float_as_uint(x);
  u = (u + 0x7FFFu + ((u >> 16) & 1u)) >> 16;   // round-to-nearest-even
  return (unsigned short)u;
}
__device__ __forceinline__ float bf2f(unsigned short h){
  return __uint_as_float(((unsigned int)h) << 16);
}

// ---------------------------------------------------------------------------
// Prep: W2 (256x256 f32), Wh (256x513 f32) -> bf16 MFMA B-fragments for
// v_mfma_f32_32x32x16_bf16. Lane l of tile (kt,ntg) holds
// B[kt*16 + (l>>5)*8 + i][ntg*32 + (l&31)], i=0..7.
// ---------------------------------------------------------------------------
__global__ void prep_kernel(const float* __restrict__ W2, const float* __restrict__ Wh,
                            unsigned short* __restrict__ w2f, unsigned short* __restrict__ whf,
                            float* __restrict__ whstop){
  int id = blockIdx.x * 256 + threadIdx.x;
  if (id < 8192){                       // W2 fragments
    int lane = id & 63; int tile = id >> 6;   // tile = kt*8 + ntg
    int ntg = tile & 7, kt = tile >> 3;
    int col = ntg * 32 + (lane & 31);
    int k0  = kt * 16 + (lane >> 5) * 8;
    unsigned int u[4];
#pragma unroll
    for (int p = 0; p < 4; ++p){
      unsigned short lo = f2bf(W2[(k0 + 2*p    ) * 256 + col]);
      unsigned short hi = f2bf(W2[(k0 + 2*p + 1) * 256 + col]);
      u[p] = (unsigned int)lo | ((unsigned int)hi << 16);
    }
    *(uint4*)(w2f + (size_t)id * 8) = make_uint4(u[0], u[1], u[2], u[3]);
  } else if (id < 24576){               // Wh fragments (asset cols 0..511)
    int id2 = id - 8192;
    int lane = id2 & 63; int tile = id2 >> 6; // tile = kt*16 + ntg
    int ntg = tile & 15, kt = tile >> 4;
    int col = ntg * 32 + (lane & 31);
    int k0  = kt * 16 + (lane >> 5) * 8;
    unsigned int u[4];
#pragma unroll
    for (int p = 0; p < 4; ++p){
      unsigned short lo = f2bf(Wh[(k0 + 2*p    ) * 513 + col]);
      unsigned short hi = f2bf(Wh[(k0 + 2*p + 1) * 513 + col]);
      u[p] = (unsigned int)lo | ((unsigned int)hi << 16);
    }
    *(uint4*)(whf + (size_t)id2 * 8) = make_uint4(u[0], u[1], u[2], u[3]);
  } else if (id < 24832){               // stop column, f32
    int k = id - 24576;
    whstop[k] = Wh[k * 513 + 512];
  }
}

// ---------------------------------------------------------------------------
// Fused kernel: 512 threads (8 waves) own 64 samples, loop 17 steps.
// Single LDS h tile [64][256] bf16, byte-XOR swizzle ((row&7)<<4).
// ---------------------------------------------------------------------------
__launch_bounds__(512, 2)
__global__ void gfn_kernel(const int* __restrict__ actions, const float* __restrict__ rp,
                           const float* __restrict__ W1, const float* __restrict__ b1,
                           const float* __restrict__ b2, const float* __restrict__ bh,
                           const unsigned short* __restrict__ w2f,
                           const unsigned short* __restrict__ whf,
                           const float* __restrict__ whstop,
                           float* __restrict__ out)
{
  __shared__ alignas(16) unsigned short h[64 * 256];    // 32 KB (h1 then h2)
  __shared__ alignas(16) float c_lds[1024];   // W1 rows 512..514 + b1
  __shared__ float b2_s[256];
  __shared__ float bh_s[513];
  __shared__ alignas(16) unsigned long long selw[64][8];
  __shared__ float pred_s[64][4];
  __shared__ float stopl[64];
  __shared__ float chosen[64];
  __shared__ float logpf_s[64];
  __shared__ float rp_s[64];
  __shared__ int   kcnt[64];
  __shared__ int   meta_s[64];     // arow | (full<<15), for the CURRENT step
  __shared__ int   isnew_s[64];
  __shared__ int   act_s[64 * 17];

  const int tid  = threadIdx.x;
  const int wave = tid >> 6;
  const int lane = tid & 63;
  const int ln5  = lane & 31;
  const int lg2  = lane >> 5;
  const int w4   = wave & 3;                 // col-group within row-tile group
  const int rowbase = (wave >> 2) << 5;      // waves 0-3: rows 0-31; 4-7: 32-63
  const int base = blockIdx.x * 64;

  // ---- init ----
  for (int i = tid; i < 1024; i += 512){
    int rrow = i >> 8, f = i & 255;
    c_lds[i] = (rrow < 3) ? W1[(512 + rrow) * 256 + f] : b1[f];
  }
  if (tid < 256) b2_s[tid] = b2[tid];
  for (int i = tid; i < 513; i += 512) bh_s[i] = bh[i];
  selw[tid >> 3][tid & 7] = 0ULL;
  for (int i = tid; i < 64 * 17; i += 512) act_s[i] = actions[base * 17 + i];
  __syncthreads();
  if (tid < 64){
    kcnt[tid] = 0; logpf_s[tid] = 0.f; rp_s[tid] = rp[base + tid];
    meta_s[tid] = act_s[tid * 17];           // step 0: full=0
  }
  float S[32];
#pragma unroll
  for (int j = 0; j < 32; ++j) S[j] = 0.f;
  __syncthreads();

  // hoisted per-thread biases (constant across steps)
  const float b2v  = b2_s[wave * 32 + ln5];
  float bhv[4];
#pragma unroll
  for (int j = 0; j < 4; ++j) bhv[j] = bh_s[(w4 * 4 + j) * 32 + ln5];

  char* hb = (char*)h;

  for (int t = 0; t < 17; ++t){
    // ---- Phase A: h1 = relu(x@W1+b1). thread = (feats lane*4.., samples wave*8..)
    {
      const float4 ck4 = *(const float4*)&c_lds[lane * 4];          // k coef
      const float4 ct4 = *(const float4*)&c_lds[256 + lane * 4];    // step coef
      const float4 cr4 = *(const float4*)&c_lds[512 + lane * 4];    // rp coef
      const float4 cb4 = *(const float4*)&c_lds[768 + lane * 4];    // b1
      float tf = (float)t;
      float cb0 = cb4.x + tf * ct4.x, cb1 = cb4.y + tf * ct4.y;
      float cb2 = cb4.z + tf * ct4.z, cb3 = cb4.w + tf * ct4.w;
#pragma unroll
      for (int s8 = 0; s8 < 8; ++s8){
        int s = wave * 8 + s8;
        float kf = (float)kcnt[s];
        float rv = rp_s[s];
        float v0 = fmaxf(S[s8*4+0] + kf * ck4.x + rv * cr4.x + cb0, 0.f);
        float v1 = fmaxf(S[s8*4+1] + kf * ck4.y + rv * cr4.y + cb1, 0.f);
        float v2 = fmaxf(S[s8*4+2] + kf * ck4.z + rv * cr4.z + cb2, 0.f);
        float v3 = fmaxf(S[s8*4+3] + kf * ck4.w + rv * cr4.w + cb3, 0.f);
        unsigned int u0 = (unsigned int)f2bf(v0) | ((unsigned int)f2bf(v1) << 16);
        unsigned int u1 = (unsigned int)f2bf(v2) | ((unsigned int)f2bf(v3) << 16);
        int byte = (s * 512 + lane * 8) ^ ((s & 7) << 4);
        *(uint2*)(hb + byte) = make_uint2(u0, u1);
      }
    }
    __syncthreads();

    // ---- Phase B: h2 = relu(h1 @ W2 + b2); wave owns cols [wave*32, +32)
    {
      f32x16 acc0, acc1;
#pragma unroll
      for (int i = 0; i < 16; ++i){ acc0[i] = 0.f; acc1[i] = 0.f; }
#pragma unroll 4
      for (int kt = 0; kt < 16; ++kt){
        int kb = kt * 32 + lg2 * 16;
        int row0 = ln5, row1 = 32 + ln5;
        bf16x8 a0 = *(const bf16x8*)(hb + ((row0 * 512 + kb) ^ ((row0 & 7) << 4)));
        bf16x8 a1 = *(const bf16x8*)(hb + ((row1 * 512 + kb) ^ ((row1 & 7) << 4)));
        bf16x8 b  = *(const bf16x8*)(w2f + ((size_t)((kt * 8 + wave) * 64 + lane)) * 8);
        acc0 = __builtin_amdgcn_mfma_f32_32x32x16_bf16(a0, b, acc0, 0, 0, 0);
        acc1 = __builtin_amdgcn_mfma_f32_32x32x16_bf16(a1, b, acc1, 0, 0, 0);
      }
      __syncthreads();   // all h1 reads done before overwriting with h2
      int col = wave * 32 + ln5;
#pragma unroll
      for (int r = 0; r < 16; ++r){
        int row = (r & 3) + ((r >> 2) << 3) + (lg2 << 2);  // C/D row map
        float v0 = fmaxf(acc0[r] + b2v, 0.f);
        *(unsigned short*)(hb + ((row * 512 + col * 2) ^ ((row & 7) << 4))) = f2bf(v0);
        int row1 = row + 32;
        float v1 = fmaxf(acc1[r] + b2v, 0.f);
        *(unsigned short*)(hb + ((row1 * 512 + col * 2) ^ ((row1 & 7) << 4))) = f2bf(v1);
      }
    }
    __syncthreads();

    // ---- stop logit (col 512): 8 threads/sample, contiguous 16B slots ----
    {
      int s = tid >> 3, f8 = tid & 7;
      float sp = 0.f;
#pragma unroll
      for (int c = 0; c < 4; ++c){
        int byte = (s * 512 + c * 128 + f8 * 16) ^ ((s & 7) << 4);
        uint4 q = *(const uint4*)(hb + byte);
        unsigned int qq[4] = {q.x, q.y, q.z, q.w};
#pragma unroll
        for (int p = 0; p < 4; ++p){
          int f = c * 64 + f8 * 8 + 2 * p;
          sp += bf2f((unsigned short)(qq[p] & 0xFFFFu)) * whstop[f]
              + bf2f((unsigned short)(qq[p] >> 16))     * whstop[f + 1];
        }
      }
      sp += __shfl_xor(sp, 1);
      sp += __shfl_xor(sp, 2);
      sp += __shfl_xor(sp, 4);
      if (f8 == 0){
        float v = sp + bh_s[512];
        if (kcnt[s] == 0) v = NEG_INF;   // mask_stop: k>0 required
        stopl[s] = v;
      }
    }

    // ---- Phase C: wave computes rows [rowbase,+32) x cols [w4*128,+128) ----
    f32x16 accC[4];
#pragma unroll
    for (int i = 0; i < 16; ++i){
      accC[0][i] = 0.f; accC[1][i] = 0.f; accC[2][i] = 0.f; accC[3][i] = 0.f;
    }
#pragma unroll 4
    for (int kt = 0; kt < 16; ++kt){
      int ar = rowbase + ln5;
      bf16x8 a0 = *(const bf16x8*)(hb + ((ar * 512 + kt * 32 + lg2 * 16) ^ ((ar & 7) << 4)));
      const unsigned short* wk = whf + ((size_t)((kt * 16 + w4 * 4) * 64 + lane)) * 8;
      bf16x8 b0 = *(const bf16x8*)(wk);
      bf16x8 b1 = *(const bf16x8*)(wk + 64 * 8);
      bf16x8 b2_ = *(const bf16x8*)(wk + 128 * 8);
      bf16x8 b3 = *(const bf16x8*)(wk + 192 * 8);
      accC[0] = __builtin_amdgcn_mfma_f32_32x32x16_bf16(a0, b0, accC[0], 0, 0, 0);
      accC[1] = __builtin_amdgcn_mfma_f32_32x32x16_bf16(a0, b1, accC[1], 0, 0, 0);
      accC[2] = __builtin_amdgcn_mfma_f32_32x32x16_bf16(a0, b2_, accC[2], 0, 0, 0);
      accC[3] = __builtin_amdgcn_mfma_f32_32x32x16_bf16(a0, b3, accC[3], 0, 0, 0);
    }

    // bias + mask + chosen-gather + no-max exp-sum (5 shuffles per row)
    {
      int col0 = w4 * 128 + ln5;
#pragma unroll
      for (int r = 0; r < 16; ++r){
        int row = rowbase + (r & 3) + ((r >> 2) << 3) + (lg2 << 2);
        ulonglong2 sw = *(const ulonglong2*)&selw[row][w4 * 2];
        int meta = meta_s[row];
        int arow = meta & 0x7FFF;
        bool full = (meta & 0x8000) != 0;
        float v0 = accC[0][r] + bhv[0];
        float v1 = accC[1][r] + bhv[1];
        float v2 = accC[2][r] + bhv[2];
        float v3 = accC[3][r] + bhv[3];
        bool m0 = full || ((sw.x >> ln5) & 1ULL);
        bool m1 = full || ((sw.x >> (32 + ln5)) & 1ULL);
        bool m2 = full || ((sw.y >> ln5) & 1ULL);
        bool m3 = full || ((sw.y >> (32 + ln5)) & 1ULL);
        v0 = m0 ? NEG_INF : v0;
        v1 = m1 ? NEG_INF : v1;
        v2 = m2 ? NEG_INF : v2;
        v3 = m3 ? NEG_INF : v3;
        if (col0      == arow) chosen[row] = v0;
        if (col0 + 32 == arow) chosen[row] = v1;
        if (col0 + 64 == arow) chosen[row] = v2;
        if (col0 + 96 == arow) chosen[row] = v3;
        float ps = __expf(v0) + __expf(v1) + __expf(v2) + __expf(v3);
        ps += __shfl_xor(ps, 1);
        ps += __shfl_xor(ps, 2);
        ps += __shfl_xor(ps, 4);
        ps += __shfl_xor(ps, 8);
        ps += __shfl_xor(ps, 16);
        if (ln5 == 0) pred_s[row][w4] = ps;
      }
    }
    __syncthreads();

    // ---- finalize: lse, logpf, state update, next-step meta ----
    if (tid < 64){
      int row = tid;
      float tot = __expf(stopl[row])
                + pred_s[row][0] + pred_s[row][1] + pred_s[row][2] + pred_s[row][3];
      float lse = __logf(tot);
      int a = act_s[row * 17 + t];
      if (a >= 0){
        float cv = (a >= 512) ? stopl[row] : chosen[row];
        logpf_s[row] += cv - lse;
      }
      int k = kcnt[row];
      int isn = 0;
      if (a >= 0 && a < 512){
        unsigned long long old = selw[row][a >> 6];
        if (!((old >> (a & 63)) & 1ULL)){
          isn = 1;
          selw[row][a >> 6] = old | (1ULL << (a & 63));
          k = k + 1;
          kcnt[row] = k;
        }
      }
      isnew_s[row] = isn;
      if (t < 16) meta_s[row] = act_s[row * 17 + t + 1] | ((k >= 16) ? 0x8000 : 0);
    }
    __syncthreads();

    // ---- layer-1 running-sum update: S += W1[a, lane*4..+4) if new ----
#pragma unroll
    for (int s8 = 0; s8 < 8; ++s8){
      int s = wave * 8 + s8;
      if (isnew_s[s]){
        int a = act_s[s * 17 + t];
        float4 v = *(const float4*)(W1 + (size_t)a * 256 + lane * 4);
        S[s8*4+0] += v.x; S[s8*4+1] += v.y; S[s8*4+2] += v.z; S[s8*4+3] += v.w;
      }
    }
  } // step loop

  if (tid < 64) out[base + tid] = logpf_s[tid];
}

extern "C" void kernel_launch(void* const* d_in, const int* in_sizes, int n_in,
                              void* d_out, int out_size, void* d_ws, size_t ws_size,
                              hipStream_t stream)
{
  const int*   actions = (const int*)d_in[0];
  const float* rp  = (const float*)d_in[1];
  const float* W1  = (const float*)d_in[2];
  const float* b1  = (const float*)d_in[3];
  const float* W2  = (const float*)d_in[4];
  const float* b2  = (const float*)d_in[5];
  const float* Wh  = (const float*)d_in[6];
  const float* bh  = (const float*)d_in[7];
  float* out = (float*)d_out;

  unsigned short* w2f = (unsigned short*)d_ws;          // 65536  bf16 (128 KB)
  unsigned short* whf = w2f + 65536;                    // 131072 bf16 (256 KB)
  float* whstop = (float*)(whf + 131072);               // 256 f32

  prep_kernel<<<97, 256, 0, stream>>>(W2, Wh, w2f, whf, whstop);
  gfn_kernel<<<1024, 512, 0, stream>>>(actions, rp, W1, b1, b2, bh, w2f, whf, whstop, out);
}